// Round 19
// baseline (675.328 us; speedup 1.0000x reference)
//
#include <hip/hip_runtime.h>

// x [T,B,NI] fp32, W [NO,NI] fp32 -> spk_rec [T,B,NO], mem_rec [T,B,NO]
// VERIFIED bit-exact (rounds 9-17): cur = per-element fold of 4 ascending-k
// FMA chains over K-blocks [512x4], combined left-assoc ((c0+c1)+c2)+c3;
// scan = fp32 separate-rounding: reset=(mem>1); mem=((0.9f*mem)+cur)-reset.
// Round 19: R18 retry with CORRECT grid (6400; R18 launched 1600 -> chain!=0
// partials never computed). K-split, 64x128, 4x8/thread, load-issue hoisted
// to the top of the compute phase; single-buffered LDS, 2 barriers/slab.
#define T_STEPS 100
#define BATCH   128
#define NI      2048
#define NO      1024
#define M_TOT   (T_STEPS * BATCH)        // 12800
#define TOTAL   (T_STEPS * BATCH * NO)   // 13107200 per output tensor
#define BNTOT   (BATCH * NO)             // 131072
#define X_ELEMS (M_TOT * NI)             // 26214400

#define BMf 64
#define BNf 128
#define BKf 32
#define LDA (BMf + 4)    // 68
#define LDB (BNf + 4)    // 132
#define NXB (NO / BNf)   // 8    n-blocks
#define NYB (M_TOT/BMf)  // 200  m-blocks
// grid = 4 chains * NYB * NXB = 6400; per XCD 800 = 8n x 100 (chain,m) pairs

__global__ __launch_bounds__(256) void gemm_chain512(const float* __restrict__ X,
                                                     const float* __restrict__ W,
                                                     float* __restrict__ p0,
                                                     float* __restrict__ p1,
                                                     float* __restrict__ p2,
                                                     float* __restrict__ p3) {
    __shared__ float As[BKf][LDA];   // transposed: As[k][m]
    __shared__ float Bs[BKf][LDB];   // transposed: Bs[k][n]

    // XCD-aware decomposition (R14): xcd owns 100 (chain,m) pairs, n fastest.
    const int orig  = blockIdx.x;
    const int xcd   = orig & 7;
    const int q     = orig >> 3;       // 0..799
    const int n0    = (q & 7) * BNf;
    const int t     = q >> 3;          // 0..99
    const int chain = t / 25;          // 0..3
    const int my    = t - chain * 25;  // 0..24
    const int m0    = (xcd * 25 + my) * BMf;
    const int kbase = chain * 512;
    float* out = (chain == 0) ? p0 : (chain == 1) ? p1 : (chain == 2) ? p2 : p3;

    const int tid = threadIdx.x;
    const int tx  = tid & 15;        // cols n0 + tx*4 + j  and  +64
    const int ty  = tid >> 4;        // rows m0 + ty*4 + i

    const int ar = tid >> 2;         // A staging row 0..63
    const int ak = (tid & 3) * 4;    // A staging k base (two quads: ak, ak+16)
    const int br = tid >> 1;         // B staging row 0..127
    const int bk = (tid & 1) * 4;    // B staging k base (quads: bk+8q)

    const float* Xp = &X[(size_t)(m0 + ar) * NI + kbase + ak];
    const float* Wp = &W[(size_t)(n0 + br) * NI + kbase + bk];

    float ch[4][8] = {};   // the 512-chain accumulators (ascending k, FMA)

    // prefetch registers (live across one compute phase only)
    float4 pa0, pa1, pb0, pb1, pb2, pb3;

    #define ISSUE_LOADS(koff)                                                  \
    {                                                                          \
        pa0 = *reinterpret_cast<const float4*>(Xp + (koff));                   \
        pa1 = *reinterpret_cast<const float4*>(Xp + (koff) + 16);              \
        pb0 = *reinterpret_cast<const float4*>(Wp + (koff));                   \
        pb1 = *reinterpret_cast<const float4*>(Wp + (koff) + 8);               \
        pb2 = *reinterpret_cast<const float4*>(Wp + (koff) + 16);              \
        pb3 = *reinterpret_cast<const float4*>(Wp + (koff) + 24);              \
    }

    // prologue: load slab 0
    ISSUE_LOADS(0);

    #pragma unroll 1
    for (int s = 0; s < 16; ++s) {
        // ---- write prefetched slab to LDS (transposed) ----
        As[ak + 0][ar] = pa0.x;  As[ak + 1][ar] = pa0.y;
        As[ak + 2][ar] = pa0.z;  As[ak + 3][ar] = pa0.w;
        As[ak + 16][ar] = pa1.x; As[ak + 17][ar] = pa1.y;
        As[ak + 18][ar] = pa1.z; As[ak + 19][ar] = pa1.w;
        Bs[bk + 0][br] = pb0.x;  Bs[bk + 1][br] = pb0.y;
        Bs[bk + 2][br] = pb0.z;  Bs[bk + 3][br] = pb0.w;
        Bs[bk + 8][br] = pb1.x;  Bs[bk + 9][br] = pb1.y;
        Bs[bk + 10][br] = pb1.z; Bs[bk + 11][br] = pb1.w;
        Bs[bk + 16][br] = pb2.x; Bs[bk + 17][br] = pb2.y;
        Bs[bk + 18][br] = pb2.z; Bs[bk + 19][br] = pb2.w;
        Bs[bk + 24][br] = pb3.x; Bs[bk + 25][br] = pb3.y;
        Bs[bk + 26][br] = pb3.z; Bs[bk + 27][br] = pb3.w;
        __syncthreads();

        // ---- issue next slab's loads NOW (latency hides under compute) ----
        if (s < 15) ISSUE_LOADS((s + 1) * BKf);

        // ---- compute: ascending k, FMA, one accumulator per element ----
        #pragma unroll
        for (int kk = 0; kk < BKf; ++kk) {
            float a[4], b[8];
            *reinterpret_cast<float4*>(&a[0]) =
                *reinterpret_cast<const float4*>(&As[kk][ty * 4]);
            *reinterpret_cast<float4*>(&b[0]) =
                *reinterpret_cast<const float4*>(&Bs[kk][tx * 4]);
            *reinterpret_cast<float4*>(&b[4]) =
                *reinterpret_cast<const float4*>(&Bs[kk][64 + tx * 4]);
            #pragma unroll
            for (int i = 0; i < 4; ++i)
                #pragma unroll
                for (int j = 0; j < 8; ++j)
                    ch[i][j] = __fmaf_rn(a[i], b[j], ch[i][j]);
        }
        __syncthreads();
    }
    #undef ISSUE_LOADS

    // ---- epilogue: store chain partial, float4 stores ----
    #pragma unroll
    for (int i = 0; i < 4; ++i) {
        const size_t rowbase = (size_t)(m0 + ty * 4 + i) * NO + n0;
        #pragma unroll
        for (int h = 0; h < 2; ++h) {
            float4 v;
            v.x = ch[i][h * 4 + 0]; v.y = ch[i][h * 4 + 1];
            v.z = ch[i][h * 4 + 2]; v.w = ch[i][h * 4 + 3];
            *reinterpret_cast<float4*>(&out[rowbase + h * 64 + tx * 4]) = v;
        }
    }
}

// ---- fused fold + LIF scan: cur = ((p0+p1)+p2)+p3 (exact ref order), then
// scan. p0 lives in the spk slot, p1 in the mem slot (same-thread RAW only).
__global__ __launch_bounds__(256) void fold_scan(float* __restrict__ spk,
                                                 float* __restrict__ memf,
                                                 const float* __restrict__ p2,
                                                 const float* __restrict__ p3) {
    const int idx = (blockIdx.x * blockDim.x + threadIdx.x) * 4;
    float4 mem = make_float4(0.f, 0.f, 0.f, 0.f);
    for (int t = 0; t < T_STEPS; ++t) {
        const size_t i = (size_t)t * BNTOT + idx;
        const float4 c0 = *reinterpret_cast<const float4*>(&spk[i]);
        const float4 c1 = *reinterpret_cast<const float4*>(&memf[i]);
        const float4 c2 = *reinterpret_cast<const float4*>(&p2[i]);
        const float4 c3 = *reinterpret_cast<const float4*>(&p3[i]);
        float4 spkv;
        #define STEP(c)                                                     \
        {                                                                   \
            const float cur = __fadd_rn(__fadd_rn(__fadd_rn(c0.c, c1.c),    \
                                                  c2.c), c3.c);             \
            const float reset = (mem.c > 1.0f) ? 1.0f : 0.0f;               \
            float tmp = __fmul_rn(0.9f, mem.c);                             \
            tmp = __fadd_rn(tmp, cur);                                      \
            mem.c = __fsub_rn(tmp, reset);                                  \
            spkv.c = (mem.c > 1.0f) ? 1.0f : 0.0f;                          \
        }
        STEP(x) STEP(y) STEP(z) STEP(w)
        #undef STEP
        *reinterpret_cast<float4*>(&spk[i])  = spkv;
        *reinterpret_cast<float4*>(&memf[i]) = mem;
    }
}

// ============== fallback path (round-13 single-kernel, proven) ==============
#define BMs 64
#define LDAs (BMs + 4)
#define LDBs (BNf + 4)
#define NYBs (M_TOT / BMs)   // 200
#define YPXs (NYBs / 8)      // 25

__global__ __launch_bounds__(256) void gemm_512fold(const float* __restrict__ X,
                                                    const float* __restrict__ W,
                                                    float* __restrict__ curOut) {
    __shared__ float As[BKf][LDAs];
    __shared__ float Bs[BKf][LDBs];
    const int orig = blockIdx.x;
    const int k_x  = orig & 7;
    const int q    = orig >> 3;
    const int m0   = (k_x * YPXs + (q >> 3)) * BMs;
    const int n0   = (q & 7) * BNf;
    const int tid = threadIdx.x;
    const int tx  = tid & 15;
    const int ty  = tid >> 4;
    const int ar = tid >> 2;
    const int ak = (tid & 3) * 4;
    const int br = tid >> 1;
    const int bk = (tid & 1) * 4;
    float ch[4][8]  = {};
    float tot[4][8] = {};
    #pragma unroll 1
    for (int k0 = 0; k0 < NI; k0 += BKf) {
        if (k0 == 512 || k0 == 1024 || k0 == 1536) {
            #pragma unroll
            for (int i = 0; i < 4; ++i)
                #pragma unroll
                for (int j = 0; j < 8; ++j) {
                    tot[i][j] = __fadd_rn(tot[i][j], ch[i][j]);
                    ch[i][j]  = 0.0f;
                }
        }
        {
            const float4 fa0 = *reinterpret_cast<const float4*>(
                &X[(size_t)(m0 + ar) * NI + k0 + ak]);
            const float4 fa1 = *reinterpret_cast<const float4*>(
                &X[(size_t)(m0 + ar) * NI + k0 + ak + 16]);
            As[ak + 0][ar] = fa0.x;  As[ak + 1][ar] = fa0.y;
            As[ak + 2][ar] = fa0.z;  As[ak + 3][ar] = fa0.w;
            As[ak + 16][ar] = fa1.x; As[ak + 17][ar] = fa1.y;
            As[ak + 18][ar] = fa1.z; As[ak + 19][ar] = fa1.w;
            #pragma unroll
            for (int qq = 0; qq < 4; ++qq) {
                const int kb = bk + qq * 8;
                const float4 fb = *reinterpret_cast<const float4*>(
                    &W[(size_t)(n0 + br) * NI + k0 + kb]);
                Bs[kb + 0][br] = fb.x; Bs[kb + 1][br] = fb.y;
                Bs[kb + 2][br] = fb.z; Bs[kb + 3][br] = fb.w;
            }
        }
        __syncthreads();
        #pragma unroll
        for (int kk = 0; kk < BKf; ++kk) {
            float a[4], b[8];
            *reinterpret_cast<float4*>(&a[0]) =
                *reinterpret_cast<const float4*>(&As[kk][ty * 4]);
            *reinterpret_cast<float4*>(&b[0]) =
                *reinterpret_cast<const float4*>(&Bs[kk][tx * 4]);
            *reinterpret_cast<float4*>(&b[4]) =
                *reinterpret_cast<const float4*>(&Bs[kk][64 + tx * 4]);
            #pragma unroll
            for (int i = 0; i < 4; ++i)
                #pragma unroll
                for (int j = 0; j < 8; ++j)
                    ch[i][j] = __fmaf_rn(a[i], b[j], ch[i][j]);
        }
        __syncthreads();
    }
    #pragma unroll
    for (int i = 0; i < 4; ++i) {
        const size_t rowbase = (size_t)(m0 + ty * 4 + i) * NO + n0;
        #pragma unroll
        for (int h = 0; h < 2; ++h) {
            float4 v;
            v.x = __fadd_rn(tot[i][h * 4 + 0], ch[i][h * 4 + 0]);
            v.y = __fadd_rn(tot[i][h * 4 + 1], ch[i][h * 4 + 1]);
            v.z = __fadd_rn(tot[i][h * 4 + 2], ch[i][h * 4 + 2]);
            v.w = __fadd_rn(tot[i][h * 4 + 3], ch[i][h * 4 + 3]);
            *reinterpret_cast<float4*>(&curOut[rowbase + h * 64 + tx * 4]) = v;
        }
    }
}

__global__ __launch_bounds__(256) void lif_scan(float* __restrict__ spk,
                                                float* __restrict__ memf) {
    const int idx = (blockIdx.x * blockDim.x + threadIdx.x) * 4;
    float4 mem = make_float4(0.f, 0.f, 0.f, 0.f);
    for (int t = 0; t < T_STEPS; ++t) {
        const size_t i = (size_t)t * BNTOT + idx;
        const float4 cur = *reinterpret_cast<const float4*>(&memf[i]);
        float4 spkv;
        #define STEP(c)                                                   \
        {                                                                 \
            const float reset = (mem.c > 1.0f) ? 1.0f : 0.0f;             \
            float tmp = __fmul_rn(0.9f, mem.c);                           \
            tmp = __fadd_rn(tmp, cur.c);                                  \
            mem.c = __fsub_rn(tmp, reset);                                \
            spkv.c = (mem.c > 1.0f) ? 1.0f : 0.0f;                        \
        }
        STEP(x) STEP(y) STEP(z) STEP(w)
        #undef STEP
        *reinterpret_cast<float4*>(&spk[i])  = spkv;
        *reinterpret_cast<float4*>(&memf[i]) = mem;
    }
}

extern "C" void kernel_launch(void* const* d_in, const int* in_sizes, int n_in,
                              void* d_out, int out_size, void* d_ws, size_t ws_size,
                              hipStream_t stream) {
    const float* X;
    const float* W;
    if (in_sizes[0] == X_ELEMS) { X = (const float*)d_in[0]; W = (const float*)d_in[1]; }
    else                        { X = (const float*)d_in[1]; W = (const float*)d_in[0]; }

    float* spk  = (float*)d_out;     // [T,B,NO]
    float* memf = spk + TOTAL;       // [T,B,NO]

    if (ws_size >= (size_t)2 * TOTAL * sizeof(float)) {
        // K-split path: chains c0->spk slot, c1->mem slot, c2/c3 -> workspace
        float* p2 = (float*)d_ws;
        float* p3 = p2 + TOTAL;
        gemm_chain512<<<4 * NXB * NYB, 256, 0, stream>>>(X, W, spk, memf, p2, p3);
        fold_scan<<<BNTOT / 4 / 256, 256, 0, stream>>>(spk, memf, p2, p3);
    } else {
        // fallback: proven round-13 path
        gemm_512fold<<<NXB * NYBs, 256, 0, stream>>>(X, W, memf);
        lif_scan<<<BNTOT / 4 / 256, 256, 0, stream>>>(spk, memf);
    }
}

// Round 20
// 633.537 us; speedup vs baseline: 1.0660x; 1.0660x over previous
//
#include <hip/hip_runtime.h>

// x [T,B,NI] fp32, W [NO,NI] fp32 -> spk_rec [T,B,NO], mem_rec [T,B,NO]
// VERIFIED bit-exact (rounds 9-19): cur = per-element fold of 4 ascending-k
// FMA chains over K-blocks [512x4], combined left-assoc ((c0+c1)+c2)+c3;
// scan = fp32 separate-rounding: reset=(mem>1); mem=((0.9f*mem)+cur)-reset.
// Round 20: REVERT to the best proven configuration (round 15, 635 us):
// K-split (one 512-chain per block), 128x128 tile, 8x8/thread, fused
// fold+scan. Structural ceiling: order-pinned scalar-FMA (no fp32 MFMA),
// GEMM ~620 us vs 341 us VALU floor; 6 further levers all null/negative.
#define T_STEPS 100
#define BATCH   128
#define NI      2048
#define NO      1024
#define M_TOT   (T_STEPS * BATCH)        // 12800
#define TOTAL   (T_STEPS * BATCH * NO)   // 13107200 per output tensor
#define BNTOT   (BATCH * NO)             // 131072
#define X_ELEMS (M_TOT * NI)             // 26214400

#define BMf 128
#define BNf 128
#define BKf 32
#define LDT 132          // padded LDS row stride (floats)
#define NXB (NO / BNf)   // 8    n-blocks
#define NYB (M_TOT/BMf)  // 100  m-blocks
// grid = NXB * NYB * 4 chains = 3200; per XCD 400 = 8n x 50 (chain,m) pairs

__global__ __launch_bounds__(256, 2) void gemm_chain512(const float* __restrict__ X,
                                                        const float* __restrict__ W,
                                                        float* __restrict__ p0,
                                                        float* __restrict__ p1,
                                                        float* __restrict__ p2,
                                                        float* __restrict__ p3) {
    __shared__ float As[BKf][LDT];   // transposed: As[k][m]
    __shared__ float Bs[BKf][LDT];   // transposed: Bs[k][n]

    // XCD-aware decomposition: xcd owns 50 (chain,m) pairs, n fastest.
    const int orig  = blockIdx.x;
    const int xcd   = orig & 7;
    const int q     = orig >> 3;        // 0..399
    const int n0    = (q & 7) * BNf;
    const int sq    = q >> 3;           // 0..49
    const int pp    = xcd * 50 + sq;    // 0..399
    const int chain = pp / 100;         // 0..3
    const int m0    = (pp - chain * 100) * BMf;
    const int kbase = chain * 512;
    float* out = (chain == 0) ? p0 : (chain == 1) ? p1 : (chain == 2) ? p2 : p3;

    const int tid = threadIdx.x;
    const int tx  = tid & 15;        // cols n0 + tx*4 + j  and  +64
    const int ty  = tid >> 4;        // rows m0 + ty*4 + i  and  +64

    const int sr = tid >> 1;         // staging row 0..127 (A and B)
    const int sk = (tid & 1) * 16;   // staging k base: 4 quads sk..sk+12

    float ch[8][8] = {};   // the 512-chain accumulators (ascending k, FMA)

    #pragma unroll 1
    for (int k0 = kbase; k0 < kbase + 512; k0 += BKf) {
        // ---- stage K-slab (transposed): 4 float4 each from X and W ----
        #pragma unroll
        for (int qq = 0; qq < 4; ++qq) {
            const int kb = sk + qq * 4;
            const float4 fa = *reinterpret_cast<const float4*>(
                &X[(size_t)(m0 + sr) * NI + k0 + kb]);
            As[kb + 0][sr] = fa.x; As[kb + 1][sr] = fa.y;
            As[kb + 2][sr] = fa.z; As[kb + 3][sr] = fa.w;
            const float4 fb = *reinterpret_cast<const float4*>(
                &W[(size_t)(n0 + sr) * NI + k0 + kb]);
            Bs[kb + 0][sr] = fb.x; Bs[kb + 1][sr] = fb.y;
            Bs[kb + 2][sr] = fb.z; Bs[kb + 3][sr] = fb.w;
        }
        __syncthreads();

        // ---- compute: ascending k, FMA, one accumulator per element ----
        #pragma unroll
        for (int kk = 0; kk < BKf; ++kk) {
            float a[8], b[8];
            *reinterpret_cast<float4*>(&a[0]) =
                *reinterpret_cast<const float4*>(&As[kk][ty * 4]);
            *reinterpret_cast<float4*>(&a[4]) =
                *reinterpret_cast<const float4*>(&As[kk][64 + ty * 4]);
            *reinterpret_cast<float4*>(&b[0]) =
                *reinterpret_cast<const float4*>(&Bs[kk][tx * 4]);
            *reinterpret_cast<float4*>(&b[4]) =
                *reinterpret_cast<const float4*>(&Bs[kk][64 + tx * 4]);
            #pragma unroll
            for (int i = 0; i < 8; ++i)
                #pragma unroll
                for (int j = 0; j < 8; ++j)
                    ch[i][j] = __fmaf_rn(a[i], b[j], ch[i][j]);
        }
        __syncthreads();
    }

    // ---- epilogue: store chain partial (quadrant layout), float4 stores ----
    #pragma unroll
    for (int i = 0; i < 8; ++i) {
        const int row = m0 + ((i < 4) ? (ty * 4 + i) : (64 + ty * 4 + i - 4));
        const size_t rowbase = (size_t)row * NO + n0;
        #pragma unroll
        for (int h = 0; h < 2; ++h) {
            float4 v;
            v.x = ch[i][h * 4 + 0]; v.y = ch[i][h * 4 + 1];
            v.z = ch[i][h * 4 + 2]; v.w = ch[i][h * 4 + 3];
            *reinterpret_cast<float4*>(&out[rowbase + h * 64 + tx * 4]) = v;
        }
    }
}

// ---- fused fold + LIF scan: cur = ((p0+p1)+p2)+p3 (exact ref order), then
// scan. p0 lives in the spk slot, p1 in the mem slot (same-thread RAW only).
__global__ __launch_bounds__(256) void fold_scan(float* __restrict__ spk,
                                                 float* __restrict__ memf,
                                                 const float* __restrict__ p2,
                                                 const float* __restrict__ p3) {
    const int idx = (blockIdx.x * blockDim.x + threadIdx.x) * 4;
    float4 mem = make_float4(0.f, 0.f, 0.f, 0.f);
    for (int t = 0; t < T_STEPS; ++t) {
        const size_t i = (size_t)t * BNTOT + idx;
        const float4 c0 = *reinterpret_cast<const float4*>(&spk[i]);
        const float4 c1 = *reinterpret_cast<const float4*>(&memf[i]);
        const float4 c2 = *reinterpret_cast<const float4*>(&p2[i]);
        const float4 c3 = *reinterpret_cast<const float4*>(&p3[i]);
        float4 spkv;
        #define STEP(c)                                                     \
        {                                                                   \
            const float cur = __fadd_rn(__fadd_rn(__fadd_rn(c0.c, c1.c),    \
                                                  c2.c), c3.c);             \
            const float reset = (mem.c > 1.0f) ? 1.0f : 0.0f;               \
            float tmp = __fmul_rn(0.9f, mem.c);                             \
            tmp = __fadd_rn(tmp, cur);                                      \
            mem.c = __fsub_rn(tmp, reset);                                  \
            spkv.c = (mem.c > 1.0f) ? 1.0f : 0.0f;                          \
        }
        STEP(x) STEP(y) STEP(z) STEP(w)
        #undef STEP
        *reinterpret_cast<float4*>(&spk[i])  = spkv;
        *reinterpret_cast<float4*>(&memf[i]) = mem;
    }
}

// ============== fallback path (round-13 single-kernel, proven) ==============
#define BMs 64
#define LDAs (BMs + 4)
#define LDBs (BNf + 4)
#define NYBs (M_TOT / BMs)   // 200
#define YPXs (NYBs / 8)      // 25

__global__ __launch_bounds__(256) void gemm_512fold(const float* __restrict__ X,
                                                    const float* __restrict__ W,
                                                    float* __restrict__ curOut) {
    __shared__ float As[BKf][LDAs];
    __shared__ float Bs[BKf][LDBs];
    const int orig = blockIdx.x;
    const int k_x  = orig & 7;
    const int q    = orig >> 3;
    const int m0   = (k_x * YPXs + (q >> 3)) * BMs;
    const int n0   = (q & 7) * BNf;
    const int tid = threadIdx.x;
    const int tx  = tid & 15;
    const int ty  = tid >> 4;
    const int ar = tid >> 2;
    const int ak = (tid & 3) * 4;
    const int br = tid >> 1;
    const int bk = (tid & 1) * 4;
    float ch[4][8]  = {};
    float tot[4][8] = {};
    #pragma unroll 1
    for (int k0 = 0; k0 < NI; k0 += BKf) {
        if (k0 == 512 || k0 == 1024 || k0 == 1536) {
            #pragma unroll
            for (int i = 0; i < 4; ++i)
                #pragma unroll
                for (int j = 0; j < 8; ++j) {
                    tot[i][j] = __fadd_rn(tot[i][j], ch[i][j]);
                    ch[i][j]  = 0.0f;
                }
        }
        {
            const float4 fa0 = *reinterpret_cast<const float4*>(
                &X[(size_t)(m0 + ar) * NI + k0 + ak]);
            const float4 fa1 = *reinterpret_cast<const float4*>(
                &X[(size_t)(m0 + ar) * NI + k0 + ak + 16]);
            As[ak + 0][ar] = fa0.x;  As[ak + 1][ar] = fa0.y;
            As[ak + 2][ar] = fa0.z;  As[ak + 3][ar] = fa0.w;
            As[ak + 16][ar] = fa1.x; As[ak + 17][ar] = fa1.y;
            As[ak + 18][ar] = fa1.z; As[ak + 19][ar] = fa1.w;
            #pragma unroll
            for (int qq = 0; qq < 4; ++qq) {
                const int kb = bk + qq * 8;
                const float4 fb = *reinterpret_cast<const float4*>(
                    &W[(size_t)(n0 + br) * NI + k0 + kb]);
                Bs[kb + 0][br] = fb.x; Bs[kb + 1][br] = fb.y;
                Bs[kb + 2][br] = fb.z; Bs[kb + 3][br] = fb.w;
            }
        }
        __syncthreads();
        #pragma unroll
        for (int kk = 0; kk < BKf; ++kk) {
            float a[4], b[8];
            *reinterpret_cast<float4*>(&a[0]) =
                *reinterpret_cast<const float4*>(&As[kk][ty * 4]);
            *reinterpret_cast<float4*>(&b[0]) =
                *reinterpret_cast<const float4*>(&Bs[kk][tx * 4]);
            *reinterpret_cast<float4*>(&b[4]) =
                *reinterpret_cast<const float4*>(&Bs[kk][64 + tx * 4]);
            #pragma unroll
            for (int i = 0; i < 4; ++i)
                #pragma unroll
                for (int j = 0; j < 8; ++j)
                    ch[i][j] = __fmaf_rn(a[i], b[j], ch[i][j]);
        }
        __syncthreads();
    }
    #pragma unroll
    for (int i = 0; i < 4; ++i) {
        const size_t rowbase = (size_t)(m0 + ty * 4 + i) * NO + n0;
        #pragma unroll
        for (int h = 0; h < 2; ++h) {
            float4 v;
            v.x = __fadd_rn(tot[i][h * 4 + 0], ch[i][h * 4 + 0]);
            v.y = __fadd_rn(tot[i][h * 4 + 1], ch[i][h * 4 + 1]);
            v.z = __fadd_rn(tot[i][h * 4 + 2], ch[i][h * 4 + 2]);
            v.w = __fadd_rn(tot[i][h * 4 + 3], ch[i][h * 4 + 3]);
            *reinterpret_cast<float4*>(&curOut[rowbase + h * 64 + tx * 4]) = v;
        }
    }
}

__global__ __launch_bounds__(256) void lif_scan(float* __restrict__ spk,
                                                float* __restrict__ memf) {
    const int idx = (blockIdx.x * blockDim.x + threadIdx.x) * 4;
    float4 mem = make_float4(0.f, 0.f, 0.f, 0.f);
    for (int t = 0; t < T_STEPS; ++t) {
        const size_t i = (size_t)t * BNTOT + idx;
        const float4 cur = *reinterpret_cast<const float4*>(&memf[i]);
        float4 spkv;
        #define STEP(c)                                                   \
        {                                                                 \
            const float reset = (mem.c > 1.0f) ? 1.0f : 0.0f;             \
            float tmp = __fmul_rn(0.9f, mem.c);                           \
            tmp = __fadd_rn(tmp, cur.c);                                  \
            mem.c = __fsub_rn(tmp, reset);                                \
            spkv.c = (mem.c > 1.0f) ? 1.0f : 0.0f;                        \
        }
        STEP(x) STEP(y) STEP(z) STEP(w)
        #undef STEP
        *reinterpret_cast<float4*>(&spk[i])  = spkv;
        *reinterpret_cast<float4*>(&memf[i]) = mem;
    }
}

extern "C" void kernel_launch(void* const* d_in, const int* in_sizes, int n_in,
                              void* d_out, int out_size, void* d_ws, size_t ws_size,
                              hipStream_t stream) {
    const float* X;
    const float* W;
    if (in_sizes[0] == X_ELEMS) { X = (const float*)d_in[0]; W = (const float*)d_in[1]; }
    else                        { X = (const float*)d_in[1]; W = (const float*)d_in[0]; }

    float* spk  = (float*)d_out;     // [T,B,NO]
    float* memf = spk + TOTAL;       // [T,B,NO]

    if (ws_size >= (size_t)2 * TOTAL * sizeof(float)) {
        // K-split path: chains c0->spk slot, c1->mem slot, c2/c3 -> workspace
        float* p2 = (float*)d_ws;
        float* p3 = p2 + TOTAL;
        gemm_chain512<<<4 * NXB * NYB, 256, 0, stream>>>(X, W, spk, memf, p2, p3);
        fold_scan<<<BNTOT / 4 / 256, 256, 0, stream>>>(spk, memf, p2, p3);
    } else {
        // fallback: proven round-13 path
        gemm_512fold<<<NXB * NYBs, 256, 0, stream>>>(X, W, memf);
        lif_scan<<<BNTOT / 4 / 256, 256, 0, stream>>>(spk, memf);
    }
}